// Round 3
// baseline (482.809 us; speedup 1.0000x reference)
//
#include <hip/hip_runtime.h>

// Problem constants: b=1, m=128, n=256, c=22
#define NC 22
#define NCC (NC*NC)        // 484 floats per (i,j) tile
#define NJ 256
#define NI 256
#define NM 128
#define JG 8               // j's per staging group
#define NQ 4               // j-quarters (one block each) -> 4 blocks/CU
#define JQ (NJ/NQ)         // 64 j's per block
#define SS (JQ/JG)         // 8 supersteps per block
#define TILE (JG*NCC)      // 3872 floats = 15488 B
#define T4   (TILE/4)      // 968 float4
#define RPT  4             // ceil(968/256) staging rounds

// Partial hi over this block's j-quarter:
//   part[q][i][m][c] = sum_{j in q} eij[i,j,c,v[m,j]] * mask_vec[v[m,j]]
// R1 block structure (256 thr, 64 VGPR, no spill) x 4 blocks/CU for latency
// hiding. R2's 1024-thr variant spilled pipeline regs -> 542 MB scratch.
__global__ __launch_bounds__(256, 4) void potts_partial(
    const int*   __restrict__ variant,   // [128,256] int32
    const float* __restrict__ eij,       // [256,256,22,22]
    const float* __restrict__ mask_vec,  // [22]
    float*       __restrict__ part)      // [4,256,128,22] workspace
{
    const int i    = blockIdx.x;
    const int q    = blockIdx.y;
    const int tid  = threadIdx.x;
    const int m    = tid & 127;
    const int half = tid >> 7;
    const int cc0  = half * 11;

    __shared__ float lds[2][TILE];       // 31 KB -> 4 blocks/CU fits 160 KB

    // Staging map: float4 f = r*256+tid covers the 968-float4 group tile.
    // Mask weight for component t of float4 f: element e=4f+t, d = e % 22
    // (valid across j since 484 % 22 == 0). Folded at LDS-write time.
    float mreg[RPT][4];
    bool  act[RPT];
    #pragma unroll
    for (int r = 0; r < RPT; ++r) {
        const int f = r * 256 + tid;
        act[r] = (f < T4);
        #pragma unroll
        for (int t = 0; t < 4; ++t)
            mreg[r][t] = act[r] ? mask_vec[(4 * f + t) % NC] : 0.f;
    }

    // This block's j-range: [q*64, q*64+64), staged 8 j's at a time.
    const float4* gsrc = (const float4*)(eij + (size_t)i * (NJ * NCC)
                                             + (size_t)q * JQ * NCC);

    float acc[11];
    #pragma unroll
    for (int k = 0; k < 11; ++k) acc[k] = 0.f;

    // Prefetch superstep 0
    float4 pf[RPT];
    #pragma unroll
    for (int r = 0; r < RPT; ++r)
        if (act[r]) pf[r] = gsrc[r * 256 + tid];

    for (int s = 0; s < SS; ++s) {
        float* buf = lds[s & 1];

        // LDS write (mask folded), lane-linear float4, conflict-free
        #pragma unroll
        for (int r = 0; r < RPT; ++r) {
            if (act[r]) {
                float4 v = pf[r];
                v.x *= mreg[r][0]; v.y *= mreg[r][1];
                v.z *= mreg[r][2]; v.w *= mreg[r][3];
                ((float4*)buf)[r * 256 + tid] = v;
            }
        }
        __syncthreads();
        // One barrier per superstep suffices with double buffering: the next
        // write to lds[(s+1)&1] happens only after all waves passed this
        // barrier, i.e. after all reads of that buffer (superstep s-1) retired.

        // Prefetch next superstep (overlaps the gather)
        if (s + 1 < SS) {
            const float4* gn = gsrc + (size_t)(s + 1) * T4;
            #pragma unroll
            for (int r = 0; r < RPT; ++r)
                if (act[r]) pf[r] = gn[r * 256 + tid];
        }

        // Variant indices for this superstep's 8 j's
        const int j0 = q * JQ + s * JG;
        const int4 va = *(const int4*)(variant + m * NJ + j0);
        const int4 vb = *(const int4*)(variant + m * NJ + j0 + 4);
        const int vs[JG] = {va.x, va.y, va.z, va.w, vb.x, vb.y, vb.z, vb.w};

        // Gather: addr = wave-uniform base + v (v in [0,22)) -> <=22 distinct
        // banks, no conflicts; equal-v lanes broadcast.
        #pragma unroll
        for (int jj = 0; jj < JG; ++jj) {
            const float* p = buf + jj * NCC + cc0 * NC + vs[jj];
            #pragma unroll
            for (int k = 0; k < 11; ++k)
                acc[k] += p[k * NC];
        }
    }

    // Partial store: [q][i][m][22] layout -> reduce kernel reads coalesced.
    // Stride between m is 88 B; block covers the full 11 KB slab -> L2 merges.
    float* pw = part + (((size_t)q * NI + i) * NM + m) * NC + cc0;
    #pragma unroll
    for (int k = 0; k < 11; ++k) pw[k] = acc[k];
}

// motifs[m,i,c] = ei[i,c] + sum_q part[q,i,m,c];  logits[m,i] = motifs[m,i,v[m,i]]
__global__ __launch_bounds__(256) void potts_reduce(
    const float* __restrict__ part,      // [4,256,128,22]
    const int*   __restrict__ variant,   // [128,256]
    const float* __restrict__ ei,        // [256,22]
    float*       __restrict__ out_motifs,// [128,256,22]
    float*       __restrict__ out_logits)// [128,256]
{
    const int i    = blockIdx.x;
    const int tid  = threadIdx.x;
    const int m    = tid & 127;
    const int half = tid >> 7;
    const int cc0  = half * 11;

    const float* p0 = part + (((size_t)0 * NI + i) * NM + m) * NC + cc0;
    const float* p1 = part + (((size_t)1 * NI + i) * NM + m) * NC + cc0;
    const float* p2 = part + (((size_t)2 * NI + i) * NM + m) * NC + cc0;
    const float* p3 = part + (((size_t)3 * NI + i) * NM + m) * NC + cc0;
    const float* eirow = ei + i * NC;
    float* mout = out_motifs + ((size_t)m * NI + i) * NC;
    const int vi = variant[m * NJ + i];

    float logit = 0.f;
    #pragma unroll
    for (int k = 0; k < 11; ++k) {
        const float v = p0[k] + p1[k] + p2[k] + p3[k] + eirow[cc0 + k];
        mout[cc0 + k] = v;
        if (cc0 + k == vi) logit = v;
    }
    if (vi >= cc0 && vi < cc0 + 11)
        out_logits[m * NI + i] = logit;
}

// variant_logit[m] = sigma * sum_i (logits[m,i]-logits[0,i]) * vm[m,i]*vm[0,i]
__global__ __launch_bounds__(64) void potts_pool(
    const float* __restrict__ logits,  // [128,256]
    const float* __restrict__ vmask,   // [128,256]
    const float* __restrict__ sigma,   // [1]
    float*       __restrict__ out_vl)  // [128]
{
    const int m    = blockIdx.x;
    const int lane = threadIdx.x;
    float s = 0.f;
    #pragma unroll
    for (int qq = 0; qq < 4; ++qq) {
        const int i = lane + 64 * qq;
        const float vl = logits[m * NI + i] - logits[i];
        s += vl * vmask[m * NI + i] * vmask[i];
    }
    #pragma unroll
    for (int off = 32; off > 0; off >>= 1)
        s += __shfl_down(s, off, 64);
    if (lane == 0) out_vl[m] = sigma[0] * s;
}

extern "C" void kernel_launch(void* const* d_in, const int* in_sizes, int n_in,
                              void* d_out, int out_size, void* d_ws, size_t ws_size,
                              hipStream_t stream) {
    const int*   variant  = (const int*)  d_in[0];  // [1,128,256] int32
    const float* vmask    = (const float*)d_in[1];  // [1,128,256]
    const float* eij      = (const float*)d_in[2];  // [1,256,256,22,22]
    const float* ei       = (const float*)d_in[3];  // [1,256,22]
    const float* mask_vec = (const float*)d_in[4];  // [22]
    const float* sigma    = (const float*)d_in[5];  // [1]

    float* out        = (float*)d_out;
    float* out_motifs = out;                        // 128*256*22
    float* out_logits = out_motifs + NM * NI * NC;  // 128*256
    float* out_vl     = out_logits + NM * NI;       // 128

    float* part = (float*)d_ws;                     // 4*256*128*22 fl = 11.5 MB

    dim3 gridA(NI, NQ);
    potts_partial<<<gridA, 256, 0, stream>>>(variant, eij, mask_vec, part);
    potts_reduce<<<NI, 256, 0, stream>>>(part, variant, ei,
                                         out_motifs, out_logits);
    potts_pool<<<NM, 64, 0, stream>>>(out_logits, vmask, sigma, out_vl);
}

// Round 4
// 215.063 us; speedup vs baseline: 2.2450x; 2.2450x over previous
//
#include <hip/hip_runtime.h>

// Problem constants: b=1, m=128, n=256, c=22
#define NC   22
#define NROW (NC*NC)        // 484 floats per (i,j) coupling row
#define NCD  (11*NC)        // 242 floats per (i,j,c-half)
#define NJ   256
#define NI   256
#define NM   128
#define JG   8              // j's per superstep
#define JH   (NJ/2)         // 128 j's per block (j-half)
#define SS   (JH/JG)        // 16 supersteps
#define TILEF (JG*NCD)      // 1936 floats = 7744 B per tile
#define TILE2 (TILEF/2)     // 968 float2
#define RPT  4              // ceil(968/256) staging rounds

// Block (i, h, jh) computes partial hi over j in [jh*128, jh*128+128) for
// c in [h*11, h*11+11):
//   part[jh][i][m][c] = sum_j eij[i,j,c,v[m,j]] * mask_vec[v[m,j]]
// 1024 blocks (4/CU, 16 waves/CU) with R1's proven no-spill register budget.
// NOTE: plain __launch_bounds__(256) — the `,4` min-waves arg in R2/R3
// correlated with ~550 MB of scratch-spill traffic (260 B/thread/superstep).
__global__ __launch_bounds__(256) void potts_partial(
    const int*   __restrict__ variant,   // [128,256] int32
    const float* __restrict__ eij,       // [256,256,22,22]
    const float* __restrict__ mask_vec,  // [22]
    float*       __restrict__ part)      // [2,256,128,22] workspace
{
    const int i   = blockIdx.x;
    const int h   = blockIdx.y;          // c-half
    const int jh  = blockIdx.z;          // j-half
    const int tid = threadIdx.x;
    const int m   = tid & 127;
    const int sub = tid >> 7;            // splits the 11 c's into 6 + 5
    const int cl0 = sub * 6;

    __shared__ float lds[2][TILEF];      // 15488 B -> 4+ blocks/CU

    // Staging map: flat float2 f2 = r*256+tid covers the 968-float2 tile.
    // Per-j chunk = 121 float2 (242 floats = 11 complete 22-rows, so
    // d = element % 22 holds within a chunk). Global per-j stride = 242
    // float2; LDS layout is the packed [j][242] tile (flat index f2).
    int   g2[RPT];
    float mreg[RPT][2];
    bool  act[RPT];
    #pragma unroll
    for (int r = 0; r < RPT; ++r) {
        const int f2 = r * 256 + tid;
        act[r] = (f2 < TILE2);
        const int fc = act[r] ? f2 : 0;
        const int jl = fc / 121;         // j within tile
        const int w  = fc % 121;         // float2 within c-half chunk
        g2[r] = jl * 242 + w;            // global float2 offset (superstep 0)
        #pragma unroll
        for (int t = 0; t < 2; ++t)
            mreg[r][t] = act[r] ? mask_vec[(2 * w + t) % NC] : 0.f;
    }

    // Global base for this block: row i, j-half jh, c-half h.
    const float2* gsrc = (const float2*)eij
                       + ((size_t)i * NJ + jh * JH) * (NROW / 2) + h * 121;

    float acc[6];
    #pragma unroll
    for (int k = 0; k < 6; ++k) acc[k] = 0.f;

    // Prefetch superstep 0
    float2 pf[RPT];
    #pragma unroll
    for (int r = 0; r < RPT; ++r)
        if (act[r]) pf[r] = gsrc[g2[r]];

    for (int s = 0; s < SS; ++s) {
        float* buf = lds[s & 1];

        // LDS write (mask folded), lane-linear float2, conflict-free
        #pragma unroll
        for (int r = 0; r < RPT; ++r) {
            if (act[r]) {
                float2 v = pf[r];
                v.x *= mreg[r][0]; v.y *= mreg[r][1];
                ((float2*)buf)[r * 256 + tid] = v;
            }
        }
        __syncthreads();
        // One barrier per superstep suffices with double buffering.

        // Prefetch next superstep (overlaps the gather)
        if (s + 1 < SS) {
            const float2* gn = gsrc + (size_t)(s + 1) * (JG * 242);
            #pragma unroll
            for (int r = 0; r < RPT; ++r)
                if (act[r]) pf[r] = gn[g2[r]];
        }

        // Variant indices for this superstep's 8 j's
        const int j0 = jh * JH + s * JG;
        const int4 va = *(const int4*)(variant + m * NJ + j0);
        const int4 vb = *(const int4*)(variant + m * NJ + j0 + 4);
        const int vs[JG] = {va.x, va.y, va.z, va.w, vb.x, vb.y, vb.z, vb.w};

        // Gather: addr = wave-uniform base + v (v in [0,22)) -> <=22 distinct
        // banks, conflict-free; equal-v lanes broadcast. sub is wave-uniform.
        #pragma unroll
        for (int jj = 0; jj < JG; ++jj) {
            const float* p = buf + jj * NCD + cl0 * NC + vs[jj];
            #pragma unroll
            for (int k = 0; k < 5; ++k)
                acc[k] += p[k * NC];
            if (!sub) acc[5] += p[5 * NC];
        }
    }

    // Partial store: [jh][i][m][22] -> reduce kernel reads it L2-resident.
    float* pw = part + (((size_t)jh * NI + i) * NM + m) * NC + h * 11 + cl0;
    #pragma unroll
    for (int k = 0; k < 5; ++k) pw[k] = acc[k];
    if (!sub) pw[5] = acc[5];
}

// motifs[m,i,c] = ei[i,c] + part[0,i,m,c] + part[1,i,m,c]
// logits[m,i]   = motifs[m,i,v[m,i]]
__global__ __launch_bounds__(256) void potts_reduce(
    const float* __restrict__ part,      // [2,256,128,22]
    const int*   __restrict__ variant,   // [128,256]
    const float* __restrict__ ei,        // [256,22]
    float*       __restrict__ out_motifs,// [128,256,22]
    float*       __restrict__ out_logits)// [128,256]
{
    const int i    = blockIdx.x;
    const int tid  = threadIdx.x;
    const int m    = tid & 127;
    const int half = tid >> 7;
    const int cc0  = half * 11;

    const float* p0 = part + (((size_t)0 * NI + i) * NM + m) * NC + cc0;
    const float* p1 = part + (((size_t)1 * NI + i) * NM + m) * NC + cc0;
    const float* eirow = ei + i * NC;
    float* mout = out_motifs + ((size_t)m * NI + i) * NC;
    const int vi = variant[m * NJ + i];

    float logit = 0.f;
    #pragma unroll
    for (int k = 0; k < 11; ++k) {
        const float v = p0[k] + p1[k] + eirow[cc0 + k];
        mout[cc0 + k] = v;
        if (cc0 + k == vi) logit = v;
    }
    if (vi >= cc0 && vi < cc0 + 11)
        out_logits[m * NI + i] = logit;
}

// variant_logit[m] = sigma * sum_i (logits[m,i]-logits[0,i]) * vm[m,i]*vm[0,i]
__global__ __launch_bounds__(64) void potts_pool(
    const float* __restrict__ logits,  // [128,256]
    const float* __restrict__ vmask,   // [128,256]
    const float* __restrict__ sigma,   // [1]
    float*       __restrict__ out_vl)  // [128]
{
    const int m    = blockIdx.x;
    const int lane = threadIdx.x;
    float s = 0.f;
    #pragma unroll
    for (int qq = 0; qq < 4; ++qq) {
        const int i = lane + 64 * qq;
        const float vl = logits[m * NI + i] - logits[i];
        s += vl * vmask[m * NI + i] * vmask[i];
    }
    #pragma unroll
    for (int off = 32; off > 0; off >>= 1)
        s += __shfl_down(s, off, 64);
    if (lane == 0) out_vl[m] = sigma[0] * s;
}

extern "C" void kernel_launch(void* const* d_in, const int* in_sizes, int n_in,
                              void* d_out, int out_size, void* d_ws, size_t ws_size,
                              hipStream_t stream) {
    const int*   variant  = (const int*)  d_in[0];  // [1,128,256] int32
    const float* vmask    = (const float*)d_in[1];  // [1,128,256]
    const float* eij      = (const float*)d_in[2];  // [1,256,256,22,22]
    const float* ei       = (const float*)d_in[3];  // [1,256,22]
    const float* mask_vec = (const float*)d_in[4];  // [22]
    const float* sigma    = (const float*)d_in[5];  // [1]

    float* out        = (float*)d_out;
    float* out_motifs = out;                        // 128*256*22
    float* out_logits = out_motifs + NM * NI * NC;  // 128*256
    float* out_vl     = out_logits + NM * NI;       // 128

    float* part = (float*)d_ws;                     // 2*256*128*22 fl = 5.8 MB

    dim3 gridA(NI, 2, 2);
    potts_partial<<<gridA, 256, 0, stream>>>(variant, eij, mask_vec, part);
    potts_reduce<<<NI, 256, 0, stream>>>(part, variant, ei,
                                         out_motifs, out_logits);
    potts_pool<<<NM, 64, 0, stream>>>(out_logits, vmask, sigma, out_vl);
}

// Round 5
// 214.027 us; speedup vs baseline: 2.2558x; 1.0048x over previous
//
#include <hip/hip_runtime.h>

// Problem constants: b=1, m=128, n=256, c=22
#define NC   22
#define NROW (NC*NC)        // 484 floats per (i,j) coupling row
#define NCD  (11*NC)        // 242 floats per (i,j,c-half)
#define NJ   256
#define NI   256
#define NM   128
#define JG   8              // j's per superstep
#define NQJ  4              // j-quarters (blockIdx.z)
#define JQ   (NJ/NQJ)       // 64 j's per block
#define SS   (JQ/JG)        // 8 supersteps
#define TILEF (JG*NCD)      // 1936 floats = 7744 B per tile
#define TILE2 (TILEF/2)     // 968 float2
#define RPT  4              // ceil(968/256) staging rounds

// Block (i, h, jq) computes partial hi over j in [jq*64, jq*64+64) for
// c in [h*11, h*11+11):
//   part[jq][i][m][c] = sum_j eij[i,j,c,v[m,j]] * mask_vec[v[m,j]]
// 2048 blocks = 8/CU = 32 waves/CU (R4 had 4/CU; partial was latency-slack
// at ~65 us vs ~25 us floors). Plain __launch_bounds__(256): the `,N`
// min-waves arg provably triggered ~550 MB scratch spill in R2/R3.
__global__ __launch_bounds__(256) void potts_partial(
    const int*   __restrict__ variant,   // [128,256] int32
    const float* __restrict__ eij,       // [256,256,22,22]
    const float* __restrict__ mask_vec,  // [22]
    float*       __restrict__ part)      // [4,256,128,22] workspace
{
    const int i   = blockIdx.x;
    const int h   = blockIdx.y;          // c-half
    const int jq  = blockIdx.z;          // j-quarter
    const int tid = threadIdx.x;
    const int m   = tid & 127;
    const int sub = tid >> 7;            // splits the 11 c's into 6 + 5
    const int cl0 = sub * 6;

    __shared__ float lds[2][TILEF];      // 15488 B -> 8 blocks/CU = 124 KB

    // Staging map: flat float2 f2 = r*256+tid covers the 968-float2 tile.
    // Per-j chunk = 121 float2 (242 floats = 11 complete 22-rows, so
    // d = element % 22 holds within a chunk). Global per-j stride = 242
    // float2; LDS layout is the packed [j][242] tile (flat index f2).
    int   g2[RPT];
    float mreg[RPT][2];
    bool  act[RPT];
    #pragma unroll
    for (int r = 0; r < RPT; ++r) {
        const int f2 = r * 256 + tid;
        act[r] = (f2 < TILE2);
        const int fc = act[r] ? f2 : 0;
        const int jl = fc / 121;         // j within tile
        const int w  = fc % 121;         // float2 within c-half chunk
        g2[r] = jl * 242 + w;            // global float2 offset (superstep 0)
        #pragma unroll
        for (int t = 0; t < 2; ++t)
            mreg[r][t] = act[r] ? mask_vec[(2 * w + t) % NC] : 0.f;
    }

    // Global base for this block: row i, j-quarter jq, c-half h.
    const float2* gsrc = (const float2*)eij
                       + ((size_t)i * NJ + jq * JQ) * (NROW / 2) + h * 121;

    float acc[6];
    #pragma unroll
    for (int k = 0; k < 6; ++k) acc[k] = 0.f;

    // Prefetch superstep 0
    float2 pf[RPT];
    #pragma unroll
    for (int r = 0; r < RPT; ++r)
        if (act[r]) pf[r] = gsrc[g2[r]];

    for (int s = 0; s < SS; ++s) {
        float* buf = lds[s & 1];

        // LDS write (mask folded), lane-linear float2, conflict-free
        #pragma unroll
        for (int r = 0; r < RPT; ++r) {
            if (act[r]) {
                float2 v = pf[r];
                v.x *= mreg[r][0]; v.y *= mreg[r][1];
                ((float2*)buf)[r * 256 + tid] = v;
            }
        }
        __syncthreads();
        // One barrier per superstep suffices with double buffering: the next
        // write to lds[(s+1)&1] happens only after all waves passed this
        // barrier, i.e. after all reads of that buffer (superstep s-1) retired.

        // Prefetch next superstep (overlaps the gather)
        if (s + 1 < SS) {
            const float2* gn = gsrc + (size_t)(s + 1) * (JG * 242);
            #pragma unroll
            for (int r = 0; r < RPT; ++r)
                if (act[r]) pf[r] = gn[g2[r]];
        }

        // Variant indices for this superstep's 8 j's
        const int j0 = jq * JQ + s * JG;
        const int4 va = *(const int4*)(variant + m * NJ + j0);
        const int4 vb = *(const int4*)(variant + m * NJ + j0 + 4);
        const int vs[JG] = {va.x, va.y, va.z, va.w, vb.x, vb.y, vb.z, vb.w};

        // Gather: addr = wave-uniform base + v (v in [0,22)) -> <=22 distinct
        // banks, conflict-free; equal-v lanes broadcast. sub is wave-uniform.
        #pragma unroll
        for (int jj = 0; jj < JG; ++jj) {
            const float* p = buf + jj * NCD + cl0 * NC + vs[jj];
            #pragma unroll
            for (int k = 0; k < 5; ++k)
                acc[k] += p[k * NC];
            if (!sub) acc[5] += p[5 * NC];
        }
    }

    // Partial store: [jq][i][m][22] -> reduce kernel reads it L2-resident.
    float* pw = part + (((size_t)jq * NI + i) * NM + m) * NC + h * 11 + cl0;
    #pragma unroll
    for (int k = 0; k < 5; ++k) pw[k] = acc[k];
    if (!sub) pw[5] = acc[5];
}

// motifs[m,i,c] = ei[i,c] + sum_jq part[jq,i,m,c]
// logits[m,i]   = motifs[m,i,v[m,i]]
__global__ __launch_bounds__(256) void potts_reduce(
    const float* __restrict__ part,      // [4,256,128,22]
    const int*   __restrict__ variant,   // [128,256]
    const float* __restrict__ ei,        // [256,22]
    float*       __restrict__ out_motifs,// [128,256,22]
    float*       __restrict__ out_logits)// [128,256]
{
    const int i    = blockIdx.x;
    const int tid  = threadIdx.x;
    const int m    = tid & 127;
    const int half = tid >> 7;
    const int cc0  = half * 11;

    const float* p0 = part + (((size_t)0 * NI + i) * NM + m) * NC + cc0;
    const float* p1 = part + (((size_t)1 * NI + i) * NM + m) * NC + cc0;
    const float* p2 = part + (((size_t)2 * NI + i) * NM + m) * NC + cc0;
    const float* p3 = part + (((size_t)3 * NI + i) * NM + m) * NC + cc0;
    const float* eirow = ei + i * NC;
    float* mout = out_motifs + ((size_t)m * NI + i) * NC;
    const int vi = variant[m * NJ + i];

    float logit = 0.f;
    #pragma unroll
    for (int k = 0; k < 11; ++k) {
        const float v = p0[k] + p1[k] + p2[k] + p3[k] + eirow[cc0 + k];
        mout[cc0 + k] = v;
        if (cc0 + k == vi) logit = v;
    }
    if (vi >= cc0 && vi < cc0 + 11)
        out_logits[m * NI + i] = logit;
}

// variant_logit[m] = sigma * sum_i (logits[m,i]-logits[0,i]) * vm[m,i]*vm[0,i]
__global__ __launch_bounds__(64) void potts_pool(
    const float* __restrict__ logits,  // [128,256]
    const float* __restrict__ vmask,   // [128,256]
    const float* __restrict__ sigma,   // [1]
    float*       __restrict__ out_vl)  // [128]
{
    const int m    = blockIdx.x;
    const int lane = threadIdx.x;
    float s = 0.f;
    #pragma unroll
    for (int qq = 0; qq < 4; ++qq) {
        const int i = lane + 64 * qq;
        const float vl = logits[m * NI + i] - logits[i];
        s += vl * vmask[m * NI + i] * vmask[i];
    }
    #pragma unroll
    for (int off = 32; off > 0; off >>= 1)
        s += __shfl_down(s, off, 64);
    if (lane == 0) out_vl[m] = sigma[0] * s;
}

extern "C" void kernel_launch(void* const* d_in, const int* in_sizes, int n_in,
                              void* d_out, int out_size, void* d_ws, size_t ws_size,
                              hipStream_t stream) {
    const int*   variant  = (const int*)  d_in[0];  // [1,128,256] int32
    const float* vmask    = (const float*)d_in[1];  // [1,128,256]
    const float* eij      = (const float*)d_in[2];  // [1,256,256,22,22]
    const float* ei       = (const float*)d_in[3];  // [1,256,22]
    const float* mask_vec = (const float*)d_in[4];  // [22]
    const float* sigma    = (const float*)d_in[5];  // [1]

    float* out        = (float*)d_out;
    float* out_motifs = out;                        // 128*256*22
    float* out_logits = out_motifs + NM * NI * NC;  // 128*256
    float* out_vl     = out_logits + NM * NI;       // 128

    float* part = (float*)d_ws;                     // 4*256*128*22 fl = 11.5 MB

    dim3 gridA(NI, 2, NQJ);
    potts_partial<<<gridA, 256, 0, stream>>>(variant, eij, mask_vec, part);
    potts_reduce<<<NI, 256, 0, stream>>>(part, variant, ei,
                                         out_motifs, out_logits);
    potts_pool<<<NM, 64, 0, stream>>>(out_logits, vmask, sigma, out_vl);
}

// Round 6
// 206.217 us; speedup vs baseline: 2.3413x; 1.0379x over previous
//
#include <hip/hip_runtime.h>

// Problem constants: b=1, m=128, n=256 (positions), c=22 classes
#define NC    22
#define NROW  (NC*NC)        // 484 floats per (i,j) coupling block
#define NJ    256
#define NI    256
#define NM    128
#define JG    8              // j's per superstep
#define NQJ   4              // j-quarters (blockIdx.y) -> 1024 blocks, 4/CU
#define JQ    (NJ/NQJ)       // 64 j's per block
#define SS    (JQ/JG)        // 8 supersteps
#define ROWDW 16             // dwords per (j,c) row: 32 bf16 (d padded 22->32)
#define JROW  (NC*ROWDW)     // 352 dwords per j
#define TILEDW (JG*JROW)     // 2816 dwords per buffer (11264 B)
#define F4PS  (JG*NROW/4)    // 968 float4 staged per superstep

typedef __attribute__((ext_vector_type(8))) short short8;  // bf16x8 A/B frag
typedef __attribute__((ext_vector_type(4))) float f32x4;   // fp32x4 C/D frag

__device__ inline uint32_t bf16rne(float x) {              // fp32 -> bf16 bits
    uint32_t u = __float_as_uint(x);
    u += 0x7FFFu + ((u >> 16) & 1u);
    return u >> 16;
}

// part[jq][i][m][c] = sum_{j in quarter} eij[i,j,c,v[m,j]] * mask_vec[v[m,j]]
// MFMA formulation: hi = A(one-hot over (j,d)) x B(em), K-block = 32 (one j).
// B-frag (lane n=c, quad q holds B[k=q*8+t][n]) reads 8 consecutive d's ==
// native eij order -> ds_read_b128, no transpose. A-frag built in VALU from
// an LDS-staged v-table (kills R5's 64-line scattered variant loads).
__global__ __launch_bounds__(256) void potts_mfma(
    const int*   __restrict__ variant,   // [128,256] int32
    const float* __restrict__ eij,       // [256,256,22,22]
    const float* __restrict__ mask_vec,  // [22]
    float*       __restrict__ part)      // [4,256,128,22] workspace
{
    const int i    = blockIdx.x;
    const int jq   = blockIdx.y;
    const int tid  = threadIdx.x;
    const int lane = tid & 63;
    const int wv   = tid >> 6;           // wave 0..3
    const int q    = lane >> 4;          // k-quad / row-quad
    const int nl   = lane & 15;          // fragment row/col index

    __shared__ uint32_t tile[2][TILEDW]; // bf16 em tiles, 22528 B
    __shared__ int      vtab[2][JG][NM]; // v[m][j] per superstep, 8192 B
    // total 30720 B -> 4 blocks/CU (123 KB), 16 waves/CU

    // Zero the d-pad (w=11..15 of every (j,c) row) once per buffer; staging
    // never writes there, MFMA reads it as B[k=22..31][*]. A has zeros at
    // d>=22 but junk here could be NaN (NaN*0=NaN) -> must be 0.
    for (int p = tid; p < 2 * JG * NC * 5; p += 256) {
        const int b  = p / (JG * NC * 5), r = p % (JG * NC * 5);
        const int jl = r / (NC * 5),     r2 = r % (NC * 5);
        tile[b][jl * JROW + (r2 / 5) * ROWDW + 11 + r2 % 5] = 0;
    }

    // Staging decomposition: float4 f4 = r*256+tid covers 968 float4 = 8 j of
    // 484 floats. 484/4=121 float4/j (no j straddle); each float4 = two
    // float2s, each within one 22-float c-row (22 even). Mask folded here.
    int   l0[4], l1[4];
    float mk[4][4];
    bool  act[4];
    #pragma unroll
    for (int r = 0; r < 4; ++r) {
        const int f4 = r * 256 + tid;
        act[r] = (f4 < F4PS);
        const int fc = act[r] ? f4 : 0;
        const int jl = fc / 121, r4 = fc % 121;
        const int f2a = 2 * r4, f2b = f2a + 1;
        const int ca = f2a / 11, wa = f2a % 11;
        const int cb = f2b / 11, wb = f2b % 11;
        l0[r] = jl * JROW + ca * ROWDW + wa;
        l1[r] = jl * JROW + cb * ROWDW + wb;
        mk[r][0] = mask_vec[2 * wa];  mk[r][1] = mask_vec[2 * wa + 1];
        mk[r][2] = mask_vec[2 * wb];  mk[r][3] = mask_vec[2 * wb + 1];
    }

    const float4* gsrc = (const float4*)eij + (size_t)(i * NJ + jq * JQ) * 121;

    // Wave-constant fragment addresses. nt=1 covers c=16..31; c>=22 lanes are
    // clamped to row 0 (real data, never NaN); their D columns are discarded.
    const int c1   = 16 + nl;
    const int off0 = nl * ROWDW + q * 4;
    const int off1 = (c1 < NC ? c1 : 0) * ROWDW + q * 4;
    const int m0a  = wv * 16;            // m-tiles: wv and wv+4
    const int m0b  = wv * 16 + 64;

    f32x4 acc_a0 = {0.f,0.f,0.f,0.f}, acc_a1 = {0.f,0.f,0.f,0.f};
    f32x4 acc_b0 = {0.f,0.f,0.f,0.f}, acc_b1 = {0.f,0.f,0.f,0.f};

    // Prefetch superstep 0 (em float4s + variant dwords)
    float4 pf[4];
    int    vr[4];
    #pragma unroll
    for (int r = 0; r < 4; ++r)
        if (act[r]) pf[r] = gsrc[r * 256 + tid];
    #pragma unroll
    for (int r = 0; r < 4; ++r) {
        const int t = r * 256 + tid;     // t<1024: m=t>>3, jj=t&7 (32B chunks)
        vr[r] = variant[(t >> 3) * NJ + jq * JQ + (t & 7)];
    }

    for (int s = 0; s < SS; ++s) {
        const int bsel = s & 1;
        uint32_t* buf = tile[bsel];

        // Stage em tile as bf16 (mask folded) + v-table
        #pragma unroll
        for (int r = 0; r < 4; ++r) {
            if (act[r]) {
                const float4 v = pf[r];
                buf[l0[r]] = bf16rne(v.x * mk[r][0])
                           | (bf16rne(v.y * mk[r][1]) << 16);
                buf[l1[r]] = bf16rne(v.z * mk[r][2])
                           | (bf16rne(v.w * mk[r][3]) << 16);
            }
        }
        #pragma unroll
        for (int r = 0; r < 4; ++r) {
            const int t = r * 256 + tid;
            vtab[bsel][t & 7][t >> 3] = vr[r];
        }
        __syncthreads();
        // One barrier per superstep: writes to buffer b at superstep s+1 occur
        // only after this barrier, which in turn requires all reads of buffer
        // b from superstep s-1 to have retired (program order). Proven in R1.

        // Prefetch next superstep
        if (s + 1 < SS) {
            const float4* gn = gsrc + (size_t)(s + 1) * F4PS;
            #pragma unroll
            for (int r = 0; r < 4; ++r)
                if (act[r]) pf[r] = gn[r * 256 + tid];
            #pragma unroll
            for (int r = 0; r < 4; ++r) {
                const int t = r * 256 + tid;
                vr[r] = variant[(t >> 3) * NJ + jq * JQ + (s + 1) * JG + (t & 7)];
            }
        }

        // 8 j's: per wave per j: 2 vtab b32 (broadcast) + 2 B-frag b128
        // (conflict-free: 64 lanes hit 64 distinct aligned 16B chunks) + 4 MFMA
        #pragma unroll
        for (int jl = 0; jl < JG; ++jl) {
            const uint32_t* jrow = buf + jl * JROW;
            const short8 bf0 = *(const short8*)(jrow + off0);
            const short8 bf1 = *(const short8*)(jrow + off1);

            const int va = vtab[bsel][jl][m0a + nl];
            const int vb = vtab[bsel][jl][m0b + nl];

            // A-frag: one-hot at d=v within k-quad q. Element t of this
            // lane is A[m][q*8+t]; pair-packed: dword u holds d=q*8+2u,+2u+1.
            // pat = 1.0bf16 in the (v&1) half; placed iff v>>1 == q*4+u.
            const uint32_t pa = 0x3F80u << ((va & 1) << 4);
            const uint32_t pb = 0x3F80u << ((vb & 1) << 4);
            const int ha = va >> 1, hb = vb >> 1, kb = q * 4;
            union { uint32_t u[4]; short8 s; } fa, fb;
            #pragma unroll
            for (int t = 0; t < 4; ++t) {
                fa.u[t] = (ha == kb + t) ? pa : 0u;
                fb.u[t] = (hb == kb + t) ? pb : 0u;
            }

            acc_a0 = __builtin_amdgcn_mfma_f32_16x16x32_bf16(fa.s, bf0, acc_a0, 0, 0, 0);
            acc_a1 = __builtin_amdgcn_mfma_f32_16x16x32_bf16(fa.s, bf1, acc_a1, 0, 0, 0);
            acc_b0 = __builtin_amdgcn_mfma_f32_16x16x32_bf16(fb.s, bf0, acc_b0, 0, 0, 0);
            acc_b1 = __builtin_amdgcn_mfma_f32_16x16x32_bf16(fb.s, bf1, acc_b1, 0, 0, 0);
        }
    }

    // Epilogue: C/D layout col=lane&15, row=(lane>>4)*4+reg (m89-verified).
    float* pbase = part + ((size_t)jq * NI + i) * NM * NC;
    #pragma unroll
    for (int t = 0; t < 4; ++t) {
        const int ra = m0a + q * 4 + t, rb = m0b + q * 4 + t;
        pbase[ra * NC + nl] = acc_a0[t];
        pbase[rb * NC + nl] = acc_b0[t];
        if (c1 < NC) {
            pbase[ra * NC + c1] = acc_a1[t];
            pbase[rb * NC + c1] = acc_b1[t];
        }
    }
}

// motifs[m,i,c] = ei[i,c] + sum_jq part[jq,i,m,c];  logits[m,i]=motifs[m,i,v[m,i]]
__global__ __launch_bounds__(256) void potts_reduce(
    const float* __restrict__ part,      // [4,256,128,22]
    const int*   __restrict__ variant,   // [128,256]
    const float* __restrict__ ei,        // [256,22]
    float*       __restrict__ out_motifs,// [128,256,22]
    float*       __restrict__ out_logits)// [128,256]
{
    const int i    = blockIdx.x;
    const int tid  = threadIdx.x;
    const int m    = tid & 127;
    const int half = tid >> 7;
    const int cc0  = half * 11;

    const float* p0 = part + (((size_t)0 * NI + i) * NM + m) * NC + cc0;
    const float* p1 = part + (((size_t)1 * NI + i) * NM + m) * NC + cc0;
    const float* p2 = part + (((size_t)2 * NI + i) * NM + m) * NC + cc0;
    const float* p3 = part + (((size_t)3 * NI + i) * NM + m) * NC + cc0;
    const float* eirow = ei + i * NC;
    float* mout = out_motifs + ((size_t)m * NI + i) * NC;
    const int vi = variant[m * NJ + i];

    float logit = 0.f;
    #pragma unroll
    for (int k = 0; k < 11; ++k) {
        const float v = p0[k] + p1[k] + p2[k] + p3[k] + eirow[cc0 + k];
        mout[cc0 + k] = v;
        if (cc0 + k == vi) logit = v;
    }
    if (vi >= cc0 && vi < cc0 + 11)
        out_logits[m * NI + i] = logit;
}

// variant_logit[m] = sigma * sum_i (logits[m,i]-logits[0,i]) * vm[m,i]*vm[0,i]
__global__ __launch_bounds__(64) void potts_pool(
    const float* __restrict__ logits,  // [128,256]
    const float* __restrict__ vmask,   // [128,256]
    const float* __restrict__ sigma,   // [1]
    float*       __restrict__ out_vl)  // [128]
{
    const int m    = blockIdx.x;
    const int lane = threadIdx.x;
    float s = 0.f;
    #pragma unroll
    for (int qq = 0; qq < 4; ++qq) {
        const int i = lane + 64 * qq;
        const float vl = logits[m * NI + i] - logits[i];
        s += vl * vmask[m * NI + i] * vmask[i];
    }
    #pragma unroll
    for (int off = 32; off > 0; off >>= 1)
        s += __shfl_down(s, off, 64);
    if (lane == 0) out_vl[m] = sigma[0] * s;
}

extern "C" void kernel_launch(void* const* d_in, const int* in_sizes, int n_in,
                              void* d_out, int out_size, void* d_ws, size_t ws_size,
                              hipStream_t stream) {
    const int*   variant  = (const int*)  d_in[0];  // [1,128,256] int32
    const float* vmask    = (const float*)d_in[1];  // [1,128,256]
    const float* eij      = (const float*)d_in[2];  // [1,256,256,22,22]
    const float* ei       = (const float*)d_in[3];  // [1,256,22]
    const float* mask_vec = (const float*)d_in[4];  // [22]
    const float* sigma    = (const float*)d_in[5];  // [1]

    float* out        = (float*)d_out;
    float* out_motifs = out;                        // 128*256*22
    float* out_logits = out_motifs + NM * NI * NC;  // 128*256
    float* out_vl     = out_logits + NM * NI;       // 128

    float* part = (float*)d_ws;                     // 4*256*128*22 fl = 11.5 MB

    dim3 gridA(NI, NQJ);
    potts_mfma<<<gridA, 256, 0, stream>>>(variant, eij, mask_vec, part);
    potts_reduce<<<NI, 256, 0, stream>>>(part, variant, ei,
                                         out_motifs, out_logits);
    potts_pool<<<NM, 64, 0, stream>>>(out_logits, vmask, sigma, out_vl);
}